// Round 6
// baseline (1514.728 us; speedup 1.0000x reference)
//
#include <hip/hip_runtime.h>

typedef float floatx4 __attribute__((ext_vector_type(4)));
typedef short shortx8 __attribute__((ext_vector_type(8)));

struct P5 { const void* p[5]; };

__device__ __forceinline__ float bf16_to_f(unsigned short u) {
    union { unsigned int i; float f; } v;
    v.i = ((unsigned int)u) << 16;
    return v.f;
}
__device__ __forceinline__ unsigned short f_to_bf16(float f) {
    union { float f; unsigned int i; } v;
    v.f = f;
    unsigned int lsb = (v.i >> 16) & 1u;
    unsigned int r = v.i + 0x7fffu + lsb;
    return (unsigned short)(r >> 16);
}

#define E_TOT 2720000
#define N_TOT 180000
#define NB 1407      // buckets of 128 global dst-slots (1407*128 = 180096)
#define BCAP 5120    // max expected bucket load ~4096+4sigma -> ample margin

// ---------------- zero ----------------
__global__ __launch_bounds__(256) void k_zero(int* __restrict__ p, int n) {
    int i = blockIdx.x * 256 + threadIdx.x;
    if (i < n) p[i] = 0;
}

// ---------------- pass A: bucketize edges ----------------
// record = (w&127)<<16 | src   (src < 50000 fits 16 bits)
__global__ __launch_bounds__(256) void k_bucketize(P5 src, P5 dst,
                                                   int* __restrict__ bcnt,
                                                   unsigned int* __restrict__ brec) {
    const int ebase[5] = {0, 640000, 1280000, 1600000, 1920000};
    const int noff[5]  = {0, 50000, 70000, 80000, 130000};
    int g = blockIdx.x * 256 + threadIdx.x;
    if (g >= E_TOT) return;
    int t = (g < 640000) ? 0 : (g < 1280000) ? 1 : (g < 1600000) ? 2 : (g < 1920000) ? 3 : 4;
    int e = g - ebase[t];
    int s = ((const int*)src.p[t])[e];
    int d = ((const int*)dst.p[t])[e];
    int w = noff[t] + d;
    int b = w >> 7;
    int pos = atomicAdd(&bcnt[b], 1);
    if (pos < BCAP)
        brec[(size_t)b * BCAP + pos] = ((unsigned int)(w & 127) << 16) | (unsigned int)s;
}

// ---------------- bucket scan (single block) ----------------
__global__ __launch_bounds__(256) void k_bscan(const int* __restrict__ bcnt,
                                               int* __restrict__ bbase) {
    __shared__ int wtot[4];
    int lane = threadIdx.x & 63;
    int wave = threadIdx.x >> 6;
    int running = 0;
    for (int c0 = 0; c0 < NB; c0 += 256) {
        int i = c0 + threadIdx.x;
        int cn = (i < NB) ? bcnt[i] : 0;
        int c = (cn < BCAP) ? cn : BCAP;
        int v = c;
#pragma unroll
        for (int d = 1; d < 64; d <<= 1) {
            int u = __shfl_up(v, d);
            if (lane >= d) v += u;
        }
        if (lane == 63) wtot[wave] = v;
        __syncthreads();
        int woff = 0;
        for (int wv = 0; wv < wave; wv++) woff += wtot[wv];
        if (i < NB) bbase[i] = running + woff + v - c;
        int tot = wtot[0] + wtot[1] + wtot[2] + wtot[3];
        __syncthreads();
        running += tot;
    }
    if (threadIdx.x == 0) bbase[NB] = running;
}

// ---------------- pass B: per-bucket CSR (grp, inv, esrc) ----------------
__global__ __launch_bounds__(128) void k_csr(const int* __restrict__ bcnt,
                                             const int* __restrict__ bbase,
                                             const unsigned int* __restrict__ brec,
                                             int* __restrict__ grp,
                                             float* __restrict__ inv,
                                             int* __restrict__ esrc) {
    __shared__ int hist[128];
    __shared__ int cur[128];
    __shared__ int wsum[2];
    const int b = blockIdx.x;
    const int tid = threadIdx.x;
    int n = bcnt[b];
    if (n > BCAP) n = BCAP;
    if (n < 0) n = 0;
    const int base = bbase[b];
    hist[tid] = 0;
    __syncthreads();
    const unsigned int* rp = brec + (size_t)b * BCAP;
    for (int i = tid; i < n; i += 128) atomicAdd(&hist[rp[i] >> 16], 1);
    __syncthreads();
    int c = hist[tid];
    int lane = tid & 63;
    int wave = tid >> 6;
    int v = c;
#pragma unroll
    for (int d = 1; d < 64; d <<= 1) {
        int u = __shfl_up(v, d);
        if (lane >= d) v += u;
    }
    if (lane == 63) wsum[wave] = v;
    __syncthreads();
    int excl = (wave ? wsum[0] : 0) + v - c;
    int w = b * 128 + tid;
    if (w < N_TOT) {
        grp[w] = base + excl;
        inv[w] = 1.0f / (float)((c > 1) ? c : 1);
        if (w == N_TOT - 1) grp[N_TOT] = base + excl + c;
    }
    cur[tid] = excl;
    __syncthreads();
    for (int i = tid; i < n; i += 128) {
        unsigned int rec = rp[i];
        int lw = rec >> 16;
        int pos = atomicAdd(&cur[lw], 1);
        esrc[base + pos] = (int)(rec & 0xffffu);
    }
}

// ---------------- cast all three fp32 embeddings -> one bf16 buffer ----------
// xb layout: drug rows [0,20000) | dis [20000,30000) | gene [30000,80000)
__global__ __launch_bounds__(256) void k_cast_all(const float* __restrict__ drug,
                                                  const float* __restrict__ dis,
                                                  const float* __restrict__ gene,
                                                  unsigned short* __restrict__ xb) {
    int i = (blockIdx.x * 256 + threadIdx.x) * 4;
    if (i >= 10240000) return;
    const float* sp;
    int off;
    if (i < 2560000) { sp = drug; off = i; }
    else if (i < 3840000) { sp = dis; off = i - 2560000; }
    else { sp = gene; off = i - 3840000; }
    floatx4 v = *(const floatx4*)(sp + off);
    ushort4 r;
    r.x = f_to_bf16(v[0]);
    r.y = f_to_bf16(v[1]);
    r.z = f_to_bf16(v[2]);
    r.w = f_to_bf16(v[3]);
    *(ushort4*)(xb + i) = r;
}

// ---------------- fused aggregate over all 180000 (type,dst) slots -----------
// One wave per slot w; lanes 0-31 handle neighbor j, lanes 32-63 neighbor j+1;
// each lane covers 4 columns (8B loads), combine via shfl_xor(32).
__global__ __launch_bounds__(256) void k_agg_all(P5 xs,
                                                 const int* __restrict__ grp,
                                                 const int* __restrict__ esrc,
                                                 const float* __restrict__ inv,
                                                 unsigned short* __restrict__ mean) {
    int w = blockIdx.x * 4 + (threadIdx.x >> 6);
    if (w >= N_TOT) return;
    const int lane = threadIdx.x & 63;
    const int half = lane >> 5;
    const int c0 = (lane & 31) << 2;
    int t = (w < 50000) ? 0 : (w < 70000) ? 1 : (w < 80000) ? 2 : (w < 130000) ? 3 : 4;
    const unsigned short* xp = (const unsigned short*)xs.p[t] + c0;
    int beg = grp[w];
    int end = grp[w + 1];
    if (beg < 0) beg = 0;
    if (end > E_TOT) end = E_TOT;
    float s0 = 0.f, s1 = 0.f, s2 = 0.f, s3 = 0.f;
    int jb = beg;
#pragma unroll 2
    for (; jb + 2 <= end; jb += 2) {
        int sA = esrc[jb + half];
        uint2 p = *(const uint2*)(xp + ((size_t)sA << 7));
        s0 += bf16_to_f((unsigned short)(p.x & 0xffffu));
        s1 += bf16_to_f((unsigned short)(p.x >> 16));
        s2 += bf16_to_f((unsigned short)(p.y & 0xffffu));
        s3 += bf16_to_f((unsigned short)(p.y >> 16));
    }
    if (jb < end && half == 0) {
        int sA = esrc[jb];
        uint2 p = *(const uint2*)(xp + ((size_t)sA << 7));
        s0 += bf16_to_f((unsigned short)(p.x & 0xffffu));
        s1 += bf16_to_f((unsigned short)(p.x >> 16));
        s2 += bf16_to_f((unsigned short)(p.y & 0xffffu));
        s3 += bf16_to_f((unsigned short)(p.y >> 16));
    }
    s0 += __shfl_xor(s0, 32);
    s1 += __shfl_xor(s1, 32);
    s2 += __shfl_xor(s2, 32);
    s3 += __shfl_xor(s3, 32);
    if (half == 0) {
        float ic = inv[w];
        uint2 o;
        o.x = (unsigned int)f_to_bf16(s0 * ic) | ((unsigned int)f_to_bf16(s1 * ic) << 16);
        o.y = (unsigned int)f_to_bf16(s2 * ic) | ((unsigned int)f_to_bf16(s3 * ic) << 16);
        *(uint2*)(mean + ((size_t)w << 7) + c0) = o;
    }
}

// ---------------- build stacked weights for one layer (fp32 in, bf16 out) ----
// Wt layouts (bf16, [128 n x K k] row-major):
//  gene  K=512: [Wl(e0) | Wl(e3) | Wl(e4) | Wr(e0)+Wr(e3)+Wr(e4)]
//  drug  K=256: [Wl(e1) | Wr(e1)]
//  dis   K=256: [Wl(e2) | Wr(e2)]
__global__ __launch_bounds__(256) void k_build_w(const float* __restrict__ Wl,
                                                 const float* __restrict__ Wr,
                                                 const float* __restrict__ bl,
                                                 int l,
                                                 unsigned short* __restrict__ Wg,
                                                 unsigned short* __restrict__ Wd,
                                                 unsigned short* __restrict__ Ws,
                                                 float* __restrict__ bg,
                                                 float* __restrict__ bd,
                                                 float* __restrict__ bs) {
    int t = blockIdx.x * 256 + threadIdx.x;
    if (t < 128 * 512) {
        int n = t >> 9;
        int kg = t & 511;
        int b = kg >> 7, k = kg & 127;
        float v;
        if (b == 0)
            v = Wl[(((size_t)l * 5 + 0) * 128 + n) * 128 + k];
        else if (b == 1)
            v = Wl[(((size_t)l * 5 + 3) * 128 + n) * 128 + k];
        else if (b == 2)
            v = Wl[(((size_t)l * 5 + 4) * 128 + n) * 128 + k];
        else
            v = Wr[(((size_t)l * 5 + 0) * 128 + n) * 128 + k] +
                Wr[(((size_t)l * 5 + 3) * 128 + n) * 128 + k] +
                Wr[(((size_t)l * 5 + 4) * 128 + n) * 128 + k];
        Wg[n * 512 + kg] = f_to_bf16(v);
    } else if (t < 131072) {
        int t2 = t - 65536;
        int which = (t2 >= 32768) ? 1 : 0;  // 0=drug(e1), 1=disease(e2)
        int t3 = which ? t2 - 32768 : t2;
        int n = t3 >> 8;
        int kg = t3 & 255;
        int b = kg >> 7, k = kg & 127;
        int ei = which ? 2 : 1;
        float v = (b == 0) ? Wl[(((size_t)l * 5 + ei) * 128 + n) * 128 + k]
                           : Wr[(((size_t)l * 5 + ei) * 128 + n) * 128 + k];
        (which ? Ws : Wd)[n * 256 + kg] = f_to_bf16(v);
    }
    if (t < 128) {
        int n = t;
        bg[n] = bl[((size_t)l * 5 + 0) * 128 + n] +
                bl[((size_t)l * 5 + 3) * 128 + n] +
                bl[((size_t)l * 5 + 4) * 128 + n];
        bd[n] = bl[((size_t)l * 5 + 1) * 128 + n];
        bs[n] = bl[((size_t)l * 5 + 2) * 128 + n];
    }
}

// ---------------- fused GEMM ----------------
// out[M,128] = relu( ( [mean_0|mean_1|mean_2|x] @ Wt^T + bias_sum ) * inv_k )
// block = 256 = 4 waves; each wave: 16 rows x 128 cols via 8 MFMA 16x16x32 tiles.
template <bool OUTBF>
__global__ __launch_bounds__(256) void k_gemm(const unsigned short* __restrict__ m0,
                                              const unsigned short* __restrict__ m1,
                                              const unsigned short* __restrict__ m2,
                                              int n_acc,
                                              const unsigned short* __restrict__ xdst,
                                              const unsigned short* __restrict__ Wt,
                                              const float* __restrict__ bias,
                                              float inv_k,
                                              void* __restrict__ out,
                                              int M) {
    const int K = (n_acc + 1) << 7;
    const int lane = threadIdx.x & 63;
    const int wave = threadIdx.x >> 6;
    const int quad = lane >> 4;
    const int l16 = lane & 15;
    const int m_base = blockIdx.x * 64 + wave * 16;
    int row = m_base + l16;
    if (row > M - 1) row = M - 1;

    floatx4 acc[8];
#pragma unroll
    for (int i = 0; i < 8; i++) acc[i] = floatx4{0.f, 0.f, 0.f, 0.f};

    for (int s = 0; s <= n_acc; s++) {
        const unsigned short* mp =
            ((s == n_acc) ? xdst : (s == 0) ? m0 : (s == 1) ? m1 : m2) + ((size_t)row << 7);
#pragma unroll
        for (int kq = 0; kq < 4; kq++) {
            const int ko = (kq << 5) + (quad << 3);
            shortx8 afrag = *(const shortx8*)(mp + ko);
            const int kglob = (s << 7) + ko;
            const unsigned short* wp = Wt + (size_t)l16 * K + kglob;
#pragma unroll
            for (int nt = 0; nt < 8; nt++) {
                shortx8 bfrag = *(const shortx8*)(wp + ((size_t)(nt << 4)) * K);
                acc[nt] = __builtin_amdgcn_mfma_f32_16x16x32_bf16(afrag, bfrag, acc[nt], 0, 0, 0);
            }
        }
    }

    // epilogue: D mapping col=lane&15, row=quad*4+reg
#pragma unroll
    for (int nt = 0; nt < 8; nt++) {
        const int col = (nt << 4) + l16;
        const float b = bias[col];
#pragma unroll
        for (int r = 0; r < 4; r++) {
            const int orow = m_base + (quad << 2) + r;
            if (orow < M) {
                float v = fmaxf((acc[nt][r] + b) * inv_k, 0.f);
                if (OUTBF)
                    ((unsigned short*)out)[((size_t)orow << 7) + col] = f_to_bf16(v);
                else
                    ((float*)out)[((size_t)orow << 7) + col] = v;
            }
        }
    }
}

extern "C" void kernel_launch(void* const* d_in, const int* in_sizes, int n_in,
                              void* d_out, int out_size, void* d_ws, size_t ws_size,
                              hipStream_t stream) {
    const float* emb_drug = (const float*)d_in[0];
    const float* emb_dis  = (const float*)d_in[1];
    const float* emb_gene = (const float*)d_in[2];
    const float* Wl = (const float*)d_in[3];
    const float* Wr = (const float*)d_in[4];
    const float* bl = (const float*)d_in[5];
    P5 srcs = {{d_in[6], d_in[8], d_in[10], d_in[12], d_in[14]}};
    P5 dsts = {{d_in[7], d_in[9], d_in[11], d_in[13], d_in[15]}};

    char* base = (char*)d_ws;
    size_t off = 0;
    auto alloc = [&](size_t bytes) -> void* {
        void* r = base + off;
        off = (off + bytes + 255) & ~(size_t)255;
        return r;
    };
    int* bcnt = (int*)alloc((size_t)(NB + 1) * 4);
    int* bbase = (int*)alloc((size_t)(NB + 1) * 4);
    unsigned int* brec = (unsigned int*)alloc((size_t)NB * BCAP * 4);
    int* grp = (int*)alloc((size_t)(N_TOT + 1) * 4);
    int* esrc = (int*)alloc((size_t)(E_TOT + 16) * 4);
    float* inv = (float*)alloc((size_t)N_TOT * 4);
    unsigned short* mean = (unsigned short*)alloc(180000ull * 128 * 2);
    unsigned short* xb = (unsigned short*)alloc(80000ull * 128 * 2);
    unsigned short* xb_drug = xb;
    unsigned short* xb_dis  = xb + 20000ull * 128;
    unsigned short* xb_gene = xb + 30000ull * 128;
    unsigned short* x1_drug = (unsigned short*)alloc(20000ull * 128 * 2);
    unsigned short* x1_dis  = (unsigned short*)alloc(10000ull * 128 * 2);
    unsigned short* x1_gene = (unsigned short*)alloc(50000ull * 128 * 2);
    unsigned short* Wg0 = (unsigned short*)alloc(128ull * 512 * 2);
    unsigned short* Wd0 = (unsigned short*)alloc(128ull * 256 * 2);
    unsigned short* Ws0 = (unsigned short*)alloc(128ull * 256 * 2);
    unsigned short* Wg1 = (unsigned short*)alloc(128ull * 512 * 2);
    unsigned short* Wd1 = (unsigned short*)alloc(128ull * 256 * 2);
    unsigned short* Ws1 = (unsigned short*)alloc(128ull * 256 * 2);
    float* bg0 = (float*)alloc(128 * 4);
    float* bd0 = (float*)alloc(128 * 4);
    float* bs0 = (float*)alloc(128 * 4);
    float* bg1 = (float*)alloc(128 * 4);
    float* bd1 = (float*)alloc(128 * 4);
    float* bs1 = (float*)alloc(128 * 4);

    // ---- CSR build (bucketed; edge structure is layer-invariant) ----
    k_zero<<<(NB + 1 + 255) / 256, 256, 0, stream>>>(bcnt, NB + 1);
    k_bucketize<<<(E_TOT + 255) / 256, 256, 0, stream>>>(srcs, dsts, bcnt, brec);
    k_bscan<<<1, 256, 0, stream>>>(bcnt, bbase);
    k_csr<<<NB, 128, 0, stream>>>(bcnt, bbase, brec, grp, inv, esrc);

    // ---- bf16 embeddings + stacked weights ----
    k_cast_all<<<(10240000 / 4 + 255) / 256, 256, 0, stream>>>(emb_drug, emb_dis,
                                                               emb_gene, xb);
    k_build_w<<<512, 256, 0, stream>>>(Wl, Wr, bl, 0, Wg0, Wd0, Ws0, bg0, bd0, bs0);
    k_build_w<<<512, 256, 0, stream>>>(Wl, Wr, bl, 1, Wg1, Wd1, Ws1, bg1, bd1, bs1);

    const long long MOFF1 = 50000ll * 128, MOFF2 = 70000ll * 128;
    const long long MOFF3 = 80000ll * 128, MOFF4 = 130000ll * 128;

    // ---- layer 1 (bf16 sources) ----
    P5 xs1 = {{xb_drug, xb_gene, xb_gene, xb_dis, xb_gene}};
    k_agg_all<<<(N_TOT + 3) / 4, 256, 0, stream>>>(xs1, grp, esrc, inv, mean);
    k_gemm<true><<<(50000 + 63) / 64, 256, 0, stream>>>(
        mean, mean + MOFF3, mean + MOFF4, 3, xb_gene, Wg0, bg0, 1.0f / 3.0f,
        x1_gene, 50000);
    k_gemm<true><<<(20000 + 63) / 64, 256, 0, stream>>>(
        mean + MOFF1, nullptr, nullptr, 1, xb_drug, Wd0, bd0, 1.0f, x1_drug, 20000);
    k_gemm<true><<<(10000 + 63) / 64, 256, 0, stream>>>(
        mean + MOFF2, nullptr, nullptr, 1, xb_dis, Ws0, bs0, 1.0f, x1_dis, 10000);

    // ---- layer 2 ----
    P5 xs2 = {{x1_drug, x1_gene, x1_gene, x1_dis, x1_gene}};
    k_agg_all<<<(N_TOT + 3) / 4, 256, 0, stream>>>(xs2, grp, esrc, inv, mean);

    float* outp = (float*)d_out;
    k_gemm<false><<<(20000 + 63) / 64, 256, 0, stream>>>(
        mean + MOFF1, nullptr, nullptr, 1, x1_drug, Wd1, bd1, 1.0f, outp, 20000);
    k_gemm<false><<<(10000 + 63) / 64, 256, 0, stream>>>(
        mean + MOFF2, nullptr, nullptr, 1, x1_dis, Ws1, bs1, 1.0f,
        outp + 20000ull * 128, 10000);
    k_gemm<false><<<(50000 + 63) / 64, 256, 0, stream>>>(
        mean, mean + MOFF3, mean + MOFF4, 3, x1_gene, Wg1, bg1, 1.0f / 3.0f,
        outp + 30000ull * 128, 50000);
}

// Round 7
// 874.042 us; speedup vs baseline: 1.7330x; 1.7330x over previous
//
#include <hip/hip_runtime.h>

typedef float floatx4 __attribute__((ext_vector_type(4)));
typedef short shortx8 __attribute__((ext_vector_type(8)));

struct P5 { const void* p[5]; };

__device__ __forceinline__ float bf16_to_f(unsigned short u) {
    union { unsigned int i; float f; } v;
    v.i = ((unsigned int)u) << 16;
    return v.f;
}
__device__ __forceinline__ unsigned short f_to_bf16(float f) {
    union { float f; unsigned int i; } v;
    v.f = f;
    unsigned int lsb = (v.i >> 16) & 1u;
    unsigned int r = v.i + 0x7fffu + lsb;
    return (unsigned short)(r >> 16);
}

#define E_TOT 2720000
#define N_TOT 180000
// scan blocking: 256 elements per block, blocks per type {196,79,40,196,196}
#define NBLK 707

__device__ __forceinline__ int blk_type(int b) {
    return (b < 196) ? 0 : (b < 275) ? 1 : (b < 315) ? 2 : (b < 511) ? 3 : 4;
}

// ---------------- zero cnti ----------------
__global__ __launch_bounds__(256) void k_zero(int* __restrict__ p, int n) {
    int i = blockIdx.x * 256 + threadIdx.x;
    if (i < n) p[i] = 0;
}

// ---------------- fused count over all 5 edge types ----------------
__global__ __launch_bounds__(256) void k_count_all(P5 dst, int* __restrict__ cnt) {
    const int ebase[5] = {0, 640000, 1280000, 1600000, 1920000};
    const int coff[5]  = {0, 50000, 70000, 80000, 130000};
    int g = blockIdx.x * 256 + threadIdx.x;
    if (g >= E_TOT) return;
    int t = (g < 640000) ? 0 : (g < 1280000) ? 1 : (g < 1600000) ? 2 : (g < 1920000) ? 3 : 4;
    int e = g - ebase[t];
    int d = ((const int*)dst.p[t])[e];
    atomicAdd(&cnt[coff[t] + d], 1);
}

// ---------------- scan stage 1: per-block sums ----------------
__global__ __launch_bounds__(256) void k_scan1(const int* __restrict__ cnt,
                                               int* __restrict__ bsum) {
    const int sizes[5] = {50000, 20000, 10000, 50000, 50000};
    const int offs[5]  = {0, 50000, 70000, 80000, 130000};
    const int bbase[5] = {0, 196, 275, 315, 511};
    int b = blockIdx.x;
    int t = blk_type(b);
    int i = (b - bbase[t]) * 256 + threadIdx.x;
    int c = (i < sizes[t]) ? cnt[offs[t] + i] : 0;
    int v = c;
    int lane = threadIdx.x & 63;
    int wave = threadIdx.x >> 6;
#pragma unroll
    for (int d = 1; d < 64; d <<= 1) v += __shfl_xor(v, d);
    __shared__ int ws[4];
    if (lane == 0) ws[wave] = v;
    __syncthreads();
    if (threadIdx.x == 0) bsum[b] = ws[0] + ws[1] + ws[2] + ws[3];
}

// ---------------- scan stage 2: per-type scan of block sums ----------------
__global__ __launch_bounds__(64) void k_scan2(const int* __restrict__ bsum,
                                              int* __restrict__ boff,
                                              int* __restrict__ rowptr) {
    const int sizes[5] = {50000, 20000, 10000, 50000, 50000};
    const int nblk[5]  = {196, 79, 40, 196, 196};
    const int bbase[5] = {0, 196, 275, 315, 511};
    const int rpo[5]   = {0, 50001, 70002, 80003, 130004};
    int t = blockIdx.x;
    int lane = threadIdx.x;
    int n = nblk[t];
    int running = 0;
    for (int chunk = 0; chunk < n; chunk += 64) {
        int i = chunk + lane;
        int c = (i < n) ? bsum[bbase[t] + i] : 0;
        int v = c;
#pragma unroll
        for (int d = 1; d < 64; d <<= 1) {
            int u = __shfl_up(v, d);
            if (lane >= d) v += u;
        }
        if (i < n) boff[bbase[t] + i] = running + v - c;
        running += __shfl(v, 63);
    }
    if (lane == 0) rowptr[rpo[t] + sizes[t]] = running;
}

// ---------------- scan stage 3: in-block exclusive scan + block offset -------
__global__ __launch_bounds__(256) void k_scan3(const int* __restrict__ cnt,
                                               const int* __restrict__ boff,
                                               int* __restrict__ rowptr,
                                               int* __restrict__ cursor,
                                               float* __restrict__ inv) {
    const int sizes[5] = {50000, 20000, 10000, 50000, 50000};
    const int offs[5]  = {0, 50000, 70000, 80000, 130000};
    const int bbase[5] = {0, 196, 275, 315, 511};
    const int rpo[5]   = {0, 50001, 70002, 80003, 130004};
    int b = blockIdx.x;
    int t = blk_type(b);
    int i = (b - bbase[t]) * 256 + threadIdx.x;
    int lane = threadIdx.x & 63;
    int wave = threadIdx.x >> 6;
    int c = (i < sizes[t]) ? cnt[offs[t] + i] : 0;
    int v = c;
#pragma unroll
    for (int d = 1; d < 64; d <<= 1) {
        int u = __shfl_up(v, d);
        if (lane >= d) v += u;
    }
    __shared__ int ws[4];
    if (lane == 63) ws[wave] = v;
    __syncthreads();
    int woff = 0;
    for (int wv = 0; wv < wave; wv++) woff += ws[wv];
    if (i < sizes[t]) {
        int excl = boff[b] + woff + v - c;
        rowptr[rpo[t] + i] = excl;
        cursor[offs[t] + i] = excl;
        inv[offs[t] + i] = 1.0f / (float)((c > 1) ? c : 1);
    }
}

// ---------------- fused permute over all 5 edge types ----------------
__global__ __launch_bounds__(256) void k_permute_all(P5 src, P5 dst,
                                                     int* __restrict__ cursor,
                                                     int* __restrict__ esrc) {
    const int ebase[5] = {0, 640000, 1280000, 1600000, 1920000};
    const int esz[5]   = {640000, 640000, 320000, 320000, 800000};
    const int coff[5]  = {0, 50000, 70000, 80000, 130000};
    int g = blockIdx.x * 256 + threadIdx.x;
    if (g >= E_TOT) return;
    int t = (g < 640000) ? 0 : (g < 1280000) ? 1 : (g < 1600000) ? 2 : (g < 1920000) ? 3 : 4;
    int e = g - ebase[t];
    int d = ((const int*)dst.p[t])[e];
    int slot = atomicAdd(&cursor[coff[t] + d], 1);
    if ((unsigned)slot < (unsigned)esz[t])  // defensive: never write OOB
        esrc[ebase[t] + slot] = ((const int*)src.p[t])[e];
}

// ---------------- cast all three fp32 embeddings -> one bf16 buffer ----------
// xb layout: drug rows [0,20000) | dis [20000,30000) | gene [30000,80000)
__global__ __launch_bounds__(256) void k_cast_all(const float* __restrict__ drug,
                                                  const float* __restrict__ dis,
                                                  const float* __restrict__ gene,
                                                  unsigned short* __restrict__ xb) {
    int i = (blockIdx.x * 256 + threadIdx.x) * 4;
    if (i >= 10240000) return;
    const float* sp;
    int off;
    if (i < 2560000) { sp = drug; off = i; }
    else if (i < 3840000) { sp = dis; off = i - 2560000; }
    else { sp = gene; off = i - 3840000; }
    floatx4 v = *(const floatx4*)(sp + off);
    ushort4 r;
    r.x = f_to_bf16(v[0]);
    r.y = f_to_bf16(v[1]);
    r.z = f_to_bf16(v[2]);
    r.w = f_to_bf16(v[3]);
    *(ushort4*)(xb + i) = r;
}

// ---------------- fused aggregate over all 180000 (type,dst) slots -----------
// One wave per slot w; lanes 0-31 handle neighbor j, lanes 32-63 neighbor j+1;
// each lane covers 4 columns (8B loads), combine via shfl_xor(32).
__global__ __launch_bounds__(256) void k_agg_all(P5 xs,
                                                 const int* __restrict__ rowptr,
                                                 const int* __restrict__ esrc,
                                                 const float* __restrict__ inv,
                                                 unsigned short* __restrict__ mean) {
    const int noff[5]  = {0, 50000, 70000, 80000, 130000};
    const int rpo[5]   = {0, 50001, 70002, 80003, 130004};
    const int ebase[5] = {0, 640000, 1280000, 1600000, 1920000};
    const int esz[5]   = {640000, 640000, 320000, 320000, 800000};
    int w = blockIdx.x * 4 + (threadIdx.x >> 6);
    if (w >= N_TOT) return;
    const int lane = threadIdx.x & 63;
    const int half = lane >> 5;
    const int c0 = (lane & 31) << 2;
    int t = (w < 50000) ? 0 : (w < 70000) ? 1 : (w < 80000) ? 2 : (w < 130000) ? 3 : 4;
    int d = w - noff[t];
    const int* rp = rowptr + rpo[t];
    int beg = rp[d];
    int end = rp[d + 1];
    if (beg < 0) beg = 0;
    if (end > esz[t]) end = esz[t];
    const int* ep = esrc + ebase[t];
    const unsigned short* xp = (const unsigned short*)xs.p[t] + c0;
    float s0 = 0.f, s1 = 0.f, s2 = 0.f, s3 = 0.f;
    int jb = beg;
#pragma unroll 2
    for (; jb + 2 <= end; jb += 2) {
        int sA = ep[jb + half];
        uint2 p = *(const uint2*)(xp + ((size_t)sA << 7));
        s0 += bf16_to_f((unsigned short)(p.x & 0xffffu));
        s1 += bf16_to_f((unsigned short)(p.x >> 16));
        s2 += bf16_to_f((unsigned short)(p.y & 0xffffu));
        s3 += bf16_to_f((unsigned short)(p.y >> 16));
    }
    if (jb < end && half == 0) {
        int sA = ep[jb];
        uint2 p = *(const uint2*)(xp + ((size_t)sA << 7));
        s0 += bf16_to_f((unsigned short)(p.x & 0xffffu));
        s1 += bf16_to_f((unsigned short)(p.x >> 16));
        s2 += bf16_to_f((unsigned short)(p.y & 0xffffu));
        s3 += bf16_to_f((unsigned short)(p.y >> 16));
    }
    s0 += __shfl_xor(s0, 32);
    s1 += __shfl_xor(s1, 32);
    s2 += __shfl_xor(s2, 32);
    s3 += __shfl_xor(s3, 32);
    if (half == 0) {
        float ic = inv[w];
        uint2 o;
        o.x = (unsigned int)f_to_bf16(s0 * ic) | ((unsigned int)f_to_bf16(s1 * ic) << 16);
        o.y = (unsigned int)f_to_bf16(s2 * ic) | ((unsigned int)f_to_bf16(s3 * ic) << 16);
        *(uint2*)(mean + ((size_t)w << 7) + c0) = o;
    }
}

// ---------------- build stacked weights for one layer (fp32 in, bf16 out) ----
// Wt layouts (bf16, [128 n x K k] row-major):
//  gene  K=512: [Wl(e0) | Wl(e3) | Wl(e4) | Wr(e0)+Wr(e3)+Wr(e4)]
//  drug  K=256: [Wl(e1) | Wr(e1)]
//  dis   K=256: [Wl(e2) | Wr(e2)]
__global__ __launch_bounds__(256) void k_build_w(const float* __restrict__ Wl,
                                                 const float* __restrict__ Wr,
                                                 const float* __restrict__ bl,
                                                 int l,
                                                 unsigned short* __restrict__ Wg,
                                                 unsigned short* __restrict__ Wd,
                                                 unsigned short* __restrict__ Ws,
                                                 float* __restrict__ bg,
                                                 float* __restrict__ bd,
                                                 float* __restrict__ bs) {
    int t = blockIdx.x * 256 + threadIdx.x;
    if (t < 128 * 512) {
        int n = t >> 9;
        int kg = t & 511;
        int b = kg >> 7, k = kg & 127;
        float v;
        if (b == 0)
            v = Wl[(((size_t)l * 5 + 0) * 128 + n) * 128 + k];
        else if (b == 1)
            v = Wl[(((size_t)l * 5 + 3) * 128 + n) * 128 + k];
        else if (b == 2)
            v = Wl[(((size_t)l * 5 + 4) * 128 + n) * 128 + k];
        else
            v = Wr[(((size_t)l * 5 + 0) * 128 + n) * 128 + k] +
                Wr[(((size_t)l * 5 + 3) * 128 + n) * 128 + k] +
                Wr[(((size_t)l * 5 + 4) * 128 + n) * 128 + k];
        Wg[n * 512 + kg] = f_to_bf16(v);
    } else if (t < 131072) {
        int t2 = t - 65536;
        int which = (t2 >= 32768) ? 1 : 0;  // 0=drug(e1), 1=disease(e2)
        int t3 = which ? t2 - 32768 : t2;
        int n = t3 >> 8;
        int kg = t3 & 255;
        int b = kg >> 7, k = kg & 127;
        int ei = which ? 2 : 1;
        float v = (b == 0) ? Wl[(((size_t)l * 5 + ei) * 128 + n) * 128 + k]
                           : Wr[(((size_t)l * 5 + ei) * 128 + n) * 128 + k];
        (which ? Ws : Wd)[n * 256 + kg] = f_to_bf16(v);
    }
    if (t < 128) {
        int n = t;
        bg[n] = bl[((size_t)l * 5 + 0) * 128 + n] +
                bl[((size_t)l * 5 + 3) * 128 + n] +
                bl[((size_t)l * 5 + 4) * 128 + n];
        bd[n] = bl[((size_t)l * 5 + 1) * 128 + n];
        bs[n] = bl[((size_t)l * 5 + 2) * 128 + n];
    }
}

// ---------------- fused GEMM ----------------
// out[M,128] = relu( ( [mean_0|mean_1|mean_2|x] @ Wt^T + bias_sum ) * inv_k )
// block = 256 = 4 waves; each wave: 16 rows x 128 cols via 8 MFMA 16x16x32 tiles.
template <bool OUTBF>
__global__ __launch_bounds__(256) void k_gemm(const unsigned short* __restrict__ m0,
                                              const unsigned short* __restrict__ m1,
                                              const unsigned short* __restrict__ m2,
                                              int n_acc,
                                              const unsigned short* __restrict__ xdst,
                                              const unsigned short* __restrict__ Wt,
                                              const float* __restrict__ bias,
                                              float inv_k,
                                              void* __restrict__ out,
                                              int M) {
    const int K = (n_acc + 1) << 7;
    const int lane = threadIdx.x & 63;
    const int wave = threadIdx.x >> 6;
    const int quad = lane >> 4;
    const int l16 = lane & 15;
    const int m_base = blockIdx.x * 64 + wave * 16;
    int row = m_base + l16;
    if (row > M - 1) row = M - 1;

    floatx4 acc[8];
#pragma unroll
    for (int i = 0; i < 8; i++) acc[i] = floatx4{0.f, 0.f, 0.f, 0.f};

    for (int s = 0; s <= n_acc; s++) {
        const unsigned short* mp =
            ((s == n_acc) ? xdst : (s == 0) ? m0 : (s == 1) ? m1 : m2) + ((size_t)row << 7);
#pragma unroll
        for (int kq = 0; kq < 4; kq++) {
            const int ko = (kq << 5) + (quad << 3);
            shortx8 afrag = *(const shortx8*)(mp + ko);
            const int kglob = (s << 7) + ko;
            const unsigned short* wp = Wt + (size_t)l16 * K + kglob;
#pragma unroll
            for (int nt = 0; nt < 8; nt++) {
                shortx8 bfrag = *(const shortx8*)(wp + ((size_t)(nt << 4)) * K);
                acc[nt] = __builtin_amdgcn_mfma_f32_16x16x32_bf16(afrag, bfrag, acc[nt], 0, 0, 0);
            }
        }
    }

    // epilogue: D mapping col=lane&15, row=quad*4+reg
#pragma unroll
    for (int nt = 0; nt < 8; nt++) {
        const int col = (nt << 4) + l16;
        const float b = bias[col];
#pragma unroll
        for (int r = 0; r < 4; r++) {
            const int orow = m_base + (quad << 2) + r;
            if (orow < M) {
                float v = fmaxf((acc[nt][r] + b) * inv_k, 0.f);
                if (OUTBF)
                    ((unsigned short*)out)[((size_t)orow << 7) + col] = f_to_bf16(v);
                else
                    ((float*)out)[((size_t)orow << 7) + col] = v;
            }
        }
    }
}

extern "C" void kernel_launch(void* const* d_in, const int* in_sizes, int n_in,
                              void* d_out, int out_size, void* d_ws, size_t ws_size,
                              hipStream_t stream) {
    const float* emb_drug = (const float*)d_in[0];
    const float* emb_dis  = (const float*)d_in[1];
    const float* emb_gene = (const float*)d_in[2];
    const float* Wl = (const float*)d_in[3];
    const float* Wr = (const float*)d_in[4];
    const float* bl = (const float*)d_in[5];
    P5 srcs = {{d_in[6], d_in[8], d_in[10], d_in[12], d_in[14]}};
    P5 dsts = {{d_in[7], d_in[9], d_in[11], d_in[13], d_in[15]}};

    char* base = (char*)d_ws;
    size_t off = 0;
    auto alloc = [&](size_t bytes) -> void* {
        void* r = base + off;
        off = (off + bytes + 255) & ~(size_t)255;
        return r;
    };
    int* cnti = (int*)alloc(180000ull * 4);
    int* rowptr = (int*)alloc(180005ull * 4);
    int* cursor = (int*)alloc(180000ull * 4);
    int* bsum = (int*)alloc((size_t)NBLK * 4);
    int* boff = (int*)alloc((size_t)NBLK * 4);
    int* esrc = (int*)alloc((size_t)(E_TOT + 16) * 4);
    float* inv = (float*)alloc(180000ull * 4);
    unsigned short* mean = (unsigned short*)alloc(180000ull * 128 * 2);
    unsigned short* xb = (unsigned short*)alloc(80000ull * 128 * 2);
    unsigned short* xb_drug = xb;
    unsigned short* xb_dis  = xb + 20000ull * 128;
    unsigned short* xb_gene = xb + 30000ull * 128;
    unsigned short* x1_drug = (unsigned short*)alloc(20000ull * 128 * 2);
    unsigned short* x1_dis  = (unsigned short*)alloc(10000ull * 128 * 2);
    unsigned short* x1_gene = (unsigned short*)alloc(50000ull * 128 * 2);
    unsigned short* Wg0 = (unsigned short*)alloc(128ull * 512 * 2);
    unsigned short* Wd0 = (unsigned short*)alloc(128ull * 256 * 2);
    unsigned short* Ws0 = (unsigned short*)alloc(128ull * 256 * 2);
    unsigned short* Wg1 = (unsigned short*)alloc(128ull * 512 * 2);
    unsigned short* Wd1 = (unsigned short*)alloc(128ull * 256 * 2);
    unsigned short* Ws1 = (unsigned short*)alloc(128ull * 256 * 2);
    float* bg0 = (float*)alloc(128 * 4);
    float* bd0 = (float*)alloc(128 * 4);
    float* bs0 = (float*)alloc(128 * 4);
    float* bg1 = (float*)alloc(128 * 4);
    float* bd1 = (float*)alloc(128 * 4);
    float* bs1 = (float*)alloc(128 * 4);

    // ---- CSR build (count -> 3-stage scan -> permute; layer-invariant) ----
    k_zero<<<(180000 + 255) / 256, 256, 0, stream>>>(cnti, 180000);
    k_count_all<<<(E_TOT + 255) / 256, 256, 0, stream>>>(dsts, cnti);
    k_scan1<<<NBLK, 256, 0, stream>>>(cnti, bsum);
    k_scan2<<<5, 64, 0, stream>>>(bsum, boff, rowptr);
    k_scan3<<<NBLK, 256, 0, stream>>>(cnti, boff, rowptr, cursor, inv);
    k_permute_all<<<(E_TOT + 255) / 256, 256, 0, stream>>>(srcs, dsts, cursor, esrc);

    // ---- bf16 embeddings + stacked weights ----
    k_cast_all<<<(10240000 / 4 + 255) / 256, 256, 0, stream>>>(emb_drug, emb_dis,
                                                               emb_gene, xb);
    k_build_w<<<512, 256, 0, stream>>>(Wl, Wr, bl, 0, Wg0, Wd0, Ws0, bg0, bd0, bs0);
    k_build_w<<<512, 256, 0, stream>>>(Wl, Wr, bl, 1, Wg1, Wd1, Ws1, bg1, bd1, bs1);

    const long long MOFF1 = 50000ll * 128, MOFF2 = 70000ll * 128;
    const long long MOFF3 = 80000ll * 128, MOFF4 = 130000ll * 128;

    // ---- layer 1 (bf16 sources) ----
    P5 xs1 = {{xb_drug, xb_gene, xb_gene, xb_dis, xb_gene}};
    k_agg_all<<<(N_TOT + 3) / 4, 256, 0, stream>>>(xs1, rowptr, esrc, inv, mean);
    k_gemm<true><<<(50000 + 63) / 64, 256, 0, stream>>>(
        mean, mean + MOFF3, mean + MOFF4, 3, xb_gene, Wg0, bg0, 1.0f / 3.0f,
        x1_gene, 50000);
    k_gemm<true><<<(20000 + 63) / 64, 256, 0, stream>>>(
        mean + MOFF1, nullptr, nullptr, 1, xb_drug, Wd0, bd0, 1.0f, x1_drug, 20000);
    k_gemm<true><<<(10000 + 63) / 64, 256, 0, stream>>>(
        mean + MOFF2, nullptr, nullptr, 1, xb_dis, Ws0, bs0, 1.0f, x1_dis, 10000);

    // ---- layer 2 ----
    P5 xs2 = {{x1_drug, x1_gene, x1_gene, x1_dis, x1_gene}};
    k_agg_all<<<(N_TOT + 3) / 4, 256, 0, stream>>>(xs2, rowptr, esrc, inv, mean);

    float* outp = (float*)d_out;
    k_gemm<false><<<(20000 + 63) / 64, 256, 0, stream>>>(
        mean + MOFF1, nullptr, nullptr, 1, x1_drug, Wd1, bd1, 1.0f, outp, 20000);
    k_gemm<false><<<(10000 + 63) / 64, 256, 0, stream>>>(
        mean + MOFF2, nullptr, nullptr, 1, x1_dis, Ws1, bs1, 1.0f,
        outp + 20000ull * 128, 10000);
    k_gemm<false><<<(50000 + 63) / 64, 256, 0, stream>>>(
        mean, mean + MOFF3, mean + MOFF4, 3, x1_gene, Wg1, bg1, 1.0f / 3.0f,
        outp + 30000ull * 128, 50000);
}

// Round 8
// 719.337 us; speedup vs baseline: 2.1057x; 1.2151x over previous
//
#include <hip/hip_runtime.h>

typedef float floatx4 __attribute__((ext_vector_type(4)));
typedef short shortx8 __attribute__((ext_vector_type(8)));

struct P5 { const void* p[5]; };

__device__ __forceinline__ float bf16_to_f(unsigned short u) {
    union { unsigned int i; float f; } v;
    v.i = ((unsigned int)u) << 16;
    return v.f;
}
__device__ __forceinline__ unsigned short f_to_bf16(float f) {
    union { float f; unsigned int i; } v;
    v.f = f;
    unsigned int lsb = (v.i >> 16) & 1u;
    unsigned int r = v.i + 0x7fffu + lsb;
    return (unsigned short)(r >> 16);
}

#define E_TOT 2720000
#define N_TOT 180000
#define CAP 96  // max degree bound: worst-type mean 32, P(deg>=96) ~ 1e-20

// ---------------- prep: zero cnt + cast embeddings + build both W stacks -----
// blocks [0,10000): cast 10.24M elems; [10000,10512): build_w l=0;
// [10512,11024): build_w l=1; [11024,11728): zero cnt.
__device__ void build_w_body(const float* Wl, const float* Wr, const float* bl,
                             int l, int t,
                             unsigned short* Wg, unsigned short* Wd,
                             unsigned short* Ws, float* bg, float* bd, float* bs) {
    if (t < 128 * 512) {
        int n = t >> 9;
        int kg = t & 511;
        int b = kg >> 7, k = kg & 127;
        float v;
        if (b == 0)
            v = Wl[(((size_t)l * 5 + 0) * 128 + n) * 128 + k];
        else if (b == 1)
            v = Wl[(((size_t)l * 5 + 3) * 128 + n) * 128 + k];
        else if (b == 2)
            v = Wl[(((size_t)l * 5 + 4) * 128 + n) * 128 + k];
        else
            v = Wr[(((size_t)l * 5 + 0) * 128 + n) * 128 + k] +
                Wr[(((size_t)l * 5 + 3) * 128 + n) * 128 + k] +
                Wr[(((size_t)l * 5 + 4) * 128 + n) * 128 + k];
        Wg[n * 512 + kg] = f_to_bf16(v);
    } else if (t < 131072) {
        int t2 = t - 65536;
        int which = (t2 >= 32768) ? 1 : 0;  // 0=drug(e1), 1=disease(e2)
        int t3 = which ? t2 - 32768 : t2;
        int n = t3 >> 8;
        int kg = t3 & 255;
        int b = kg >> 7, k = kg & 127;
        int ei = which ? 2 : 1;
        float v = (b == 0) ? Wl[(((size_t)l * 5 + ei) * 128 + n) * 128 + k]
                           : Wr[(((size_t)l * 5 + ei) * 128 + n) * 128 + k];
        (which ? Ws : Wd)[n * 256 + kg] = f_to_bf16(v);
    }
    if (t < 128) {
        int n = t;
        bg[n] = bl[((size_t)l * 5 + 0) * 128 + n] +
                bl[((size_t)l * 5 + 3) * 128 + n] +
                bl[((size_t)l * 5 + 4) * 128 + n];
        bd[n] = bl[((size_t)l * 5 + 1) * 128 + n];
        bs[n] = bl[((size_t)l * 5 + 2) * 128 + n];
    }
}

__global__ __launch_bounds__(256) void k_prep(const float* __restrict__ drug,
                                              const float* __restrict__ dis,
                                              const float* __restrict__ gene,
                                              unsigned short* __restrict__ xb,
                                              const float* __restrict__ Wl,
                                              const float* __restrict__ Wr,
                                              const float* __restrict__ bl,
                                              unsigned short* __restrict__ Wg0,
                                              unsigned short* __restrict__ Wd0,
                                              unsigned short* __restrict__ Ws0,
                                              float* __restrict__ bg0,
                                              float* __restrict__ bd0,
                                              float* __restrict__ bs0,
                                              unsigned short* __restrict__ Wg1,
                                              unsigned short* __restrict__ Wd1,
                                              unsigned short* __restrict__ Ws1,
                                              float* __restrict__ bg1,
                                              float* __restrict__ bd1,
                                              float* __restrict__ bs1,
                                              int* __restrict__ cnt) {
    int b = blockIdx.x;
    if (b < 10000) {
        int i = (b * 256 + threadIdx.x) * 4;
        if (i >= 10240000) return;
        const float* sp;
        int off;
        if (i < 2560000) { sp = drug; off = i; }
        else if (i < 3840000) { sp = dis; off = i - 2560000; }
        else { sp = gene; off = i - 3840000; }
        floatx4 v = *(const floatx4*)(sp + off);
        ushort4 r;
        r.x = f_to_bf16(v[0]);
        r.y = f_to_bf16(v[1]);
        r.z = f_to_bf16(v[2]);
        r.w = f_to_bf16(v[3]);
        *(ushort4*)(xb + i) = r;
    } else if (b < 10512) {
        build_w_body(Wl, Wr, bl, 0, (b - 10000) * 256 + threadIdx.x,
                     Wg0, Wd0, Ws0, bg0, bd0, bs0);
    } else if (b < 11024) {
        build_w_body(Wl, Wr, bl, 1, (b - 10512) * 256 + threadIdx.x,
                     Wg1, Wd1, Ws1, bg1, bd1, bs1);
    } else {
        int i = (b - 11024) * 256 + threadIdx.x;
        if (i < N_TOT) cnt[i] = 0;
    }
}

// ---------------- single-pass fixed-capacity adjacency build ----------------
// esF[w*CAP + slot] = (ushort)src, slot = atomicAdd(cnt[w]).
__global__ __launch_bounds__(256) void k_fill(P5 src, P5 dst,
                                              int* __restrict__ cnt,
                                              unsigned short* __restrict__ esF) {
    const int ebase[5] = {0, 640000, 1280000, 1600000, 1920000};
    const int noff[5]  = {0, 50000, 70000, 80000, 130000};
    int g = blockIdx.x * 256 + threadIdx.x;
    if (g >= E_TOT) return;
    int t = (g < 640000) ? 0 : (g < 1280000) ? 1 : (g < 1600000) ? 2 : (g < 1920000) ? 3 : 4;
    int e = g - ebase[t];
    int s = ((const int*)src.p[t])[e];
    int d = ((const int*)dst.p[t])[e];
    int w = noff[t] + d;
    int slot = atomicAdd(&cnt[w], 1);
    if (slot < CAP) esF[(size_t)w * CAP + slot] = (unsigned short)s;
}

// ---------------- fused aggregate over all 180000 (type,dst) slots -----------
// One wave per slot w; lanes 0-31 handle neighbor j, lanes 32-63 neighbor j+1;
// each lane covers 4 columns (8B loads), combine via shfl_xor(32).
__global__ __launch_bounds__(256) void k_agg_all(P5 xs,
                                                 const int* __restrict__ cnt,
                                                 const unsigned short* __restrict__ esF,
                                                 unsigned short* __restrict__ mean) {
    int w = blockIdx.x * 4 + (threadIdx.x >> 6);
    if (w >= N_TOT) return;
    const int lane = threadIdx.x & 63;
    const int half = lane >> 5;
    const int c0 = (lane & 31) << 2;
    int t = (w < 50000) ? 0 : (w < 70000) ? 1 : (w < 80000) ? 2 : (w < 130000) ? 3 : 4;
    int n = cnt[w];
    if (n > CAP) n = CAP;
    if (n < 0) n = 0;
    const unsigned short* ep = esF + (size_t)w * CAP;
    const unsigned short* xp = (const unsigned short*)xs.p[t] + c0;
    float s0 = 0.f, s1 = 0.f, s2 = 0.f, s3 = 0.f;
    int jb = 0;
#pragma unroll 2
    for (; jb + 2 <= n; jb += 2) {
        int sA = ep[jb + half];
        uint2 p = *(const uint2*)(xp + ((size_t)sA << 7));
        s0 += bf16_to_f((unsigned short)(p.x & 0xffffu));
        s1 += bf16_to_f((unsigned short)(p.x >> 16));
        s2 += bf16_to_f((unsigned short)(p.y & 0xffffu));
        s3 += bf16_to_f((unsigned short)(p.y >> 16));
    }
    if (jb < n && half == 0) {
        int sA = ep[jb];
        uint2 p = *(const uint2*)(xp + ((size_t)sA << 7));
        s0 += bf16_to_f((unsigned short)(p.x & 0xffffu));
        s1 += bf16_to_f((unsigned short)(p.x >> 16));
        s2 += bf16_to_f((unsigned short)(p.y & 0xffffu));
        s3 += bf16_to_f((unsigned short)(p.y >> 16));
    }
    s0 += __shfl_xor(s0, 32);
    s1 += __shfl_xor(s1, 32);
    s2 += __shfl_xor(s2, 32);
    s3 += __shfl_xor(s3, 32);
    if (half == 0) {
        float ic = 1.0f / (float)((n > 1) ? n : 1);
        uint2 o;
        o.x = (unsigned int)f_to_bf16(s0 * ic) | ((unsigned int)f_to_bf16(s1 * ic) << 16);
        o.y = (unsigned int)f_to_bf16(s2 * ic) | ((unsigned int)f_to_bf16(s3 * ic) << 16);
        *(uint2*)(mean + ((size_t)w << 7) + c0) = o;
    }
}

// ---------------- fused GEMM ----------------
// out[M,128] = relu( ( [mean_0|mean_1|mean_2|x] @ Wt^T + bias_sum ) * inv_k )
// block = 256 = 4 waves; each wave: 16 rows x 128 cols via 8 MFMA 16x16x32 tiles.
template <bool OUTBF>
__global__ __launch_bounds__(256) void k_gemm(const unsigned short* __restrict__ m0,
                                              const unsigned short* __restrict__ m1,
                                              const unsigned short* __restrict__ m2,
                                              int n_acc,
                                              const unsigned short* __restrict__ xdst,
                                              const unsigned short* __restrict__ Wt,
                                              const float* __restrict__ bias,
                                              float inv_k,
                                              void* __restrict__ out,
                                              int M) {
    const int K = (n_acc + 1) << 7;
    const int lane = threadIdx.x & 63;
    const int wave = threadIdx.x >> 6;
    const int quad = lane >> 4;
    const int l16 = lane & 15;
    const int m_base = blockIdx.x * 64 + wave * 16;
    int row = m_base + l16;
    if (row > M - 1) row = M - 1;

    floatx4 acc[8];
#pragma unroll
    for (int i = 0; i < 8; i++) acc[i] = floatx4{0.f, 0.f, 0.f, 0.f};

    for (int s = 0; s <= n_acc; s++) {
        const unsigned short* mp =
            ((s == n_acc) ? xdst : (s == 0) ? m0 : (s == 1) ? m1 : m2) + ((size_t)row << 7);
#pragma unroll
        for (int kq = 0; kq < 4; kq++) {
            const int ko = (kq << 5) + (quad << 3);
            shortx8 afrag = *(const shortx8*)(mp + ko);
            const int kglob = (s << 7) + ko;
            const unsigned short* wp = Wt + (size_t)l16 * K + kglob;
#pragma unroll
            for (int nt = 0; nt < 8; nt++) {
                shortx8 bfrag = *(const shortx8*)(wp + ((size_t)(nt << 4)) * K);
                acc[nt] = __builtin_amdgcn_mfma_f32_16x16x32_bf16(afrag, bfrag, acc[nt], 0, 0, 0);
            }
        }
    }

    // epilogue: D mapping col=lane&15, row=quad*4+reg
#pragma unroll
    for (int nt = 0; nt < 8; nt++) {
        const int col = (nt << 4) + l16;
        const float b = bias[col];
#pragma unroll
        for (int r = 0; r < 4; r++) {
            const int orow = m_base + (quad << 2) + r;
            if (orow < M) {
                float v = fmaxf((acc[nt][r] + b) * inv_k, 0.f);
                if (OUTBF)
                    ((unsigned short*)out)[((size_t)orow << 7) + col] = f_to_bf16(v);
                else
                    ((float*)out)[((size_t)orow << 7) + col] = v;
            }
        }
    }
}

extern "C" void kernel_launch(void* const* d_in, const int* in_sizes, int n_in,
                              void* d_out, int out_size, void* d_ws, size_t ws_size,
                              hipStream_t stream) {
    const float* emb_drug = (const float*)d_in[0];
    const float* emb_dis  = (const float*)d_in[1];
    const float* emb_gene = (const float*)d_in[2];
    const float* Wl = (const float*)d_in[3];
    const float* Wr = (const float*)d_in[4];
    const float* bl = (const float*)d_in[5];
    P5 srcs = {{d_in[6], d_in[8], d_in[10], d_in[12], d_in[14]}};
    P5 dsts = {{d_in[7], d_in[9], d_in[11], d_in[13], d_in[15]}};

    char* base = (char*)d_ws;
    size_t off = 0;
    auto alloc = [&](size_t bytes) -> void* {
        void* r = base + off;
        off = (off + bytes + 255) & ~(size_t)255;
        return r;
    };
    int* cnt = (int*)alloc((size_t)N_TOT * 4);
    unsigned short* esF = (unsigned short*)alloc((size_t)N_TOT * CAP * 2);
    unsigned short* mean = (unsigned short*)alloc(180000ull * 128 * 2);
    unsigned short* xb = (unsigned short*)alloc(80000ull * 128 * 2);
    unsigned short* xb_drug = xb;
    unsigned short* xb_dis  = xb + 20000ull * 128;
    unsigned short* xb_gene = xb + 30000ull * 128;
    unsigned short* x1_drug = (unsigned short*)alloc(20000ull * 128 * 2);
    unsigned short* x1_dis  = (unsigned short*)alloc(10000ull * 128 * 2);
    unsigned short* x1_gene = (unsigned short*)alloc(50000ull * 128 * 2);
    unsigned short* Wg0 = (unsigned short*)alloc(128ull * 512 * 2);
    unsigned short* Wd0 = (unsigned short*)alloc(128ull * 256 * 2);
    unsigned short* Ws0 = (unsigned short*)alloc(128ull * 256 * 2);
    unsigned short* Wg1 = (unsigned short*)alloc(128ull * 512 * 2);
    unsigned short* Wd1 = (unsigned short*)alloc(128ull * 256 * 2);
    unsigned short* Ws1 = (unsigned short*)alloc(128ull * 256 * 2);
    float* bg0 = (float*)alloc(128 * 4);
    float* bd0 = (float*)alloc(128 * 4);
    float* bs0 = (float*)alloc(128 * 4);
    float* bg1 = (float*)alloc(128 * 4);
    float* bd1 = (float*)alloc(128 * 4);
    float* bs1 = (float*)alloc(128 * 4);

    // ---- prep (zero cnt | cast embeddings | build W stacks) ----
    k_prep<<<11728, 256, 0, stream>>>(emb_drug, emb_dis, emb_gene, xb, Wl, Wr, bl,
                                      Wg0, Wd0, Ws0, bg0, bd0, bs0,
                                      Wg1, Wd1, Ws1, bg1, bd1, bs1, cnt);

    // ---- single-pass adjacency build (layer-invariant) ----
    k_fill<<<(E_TOT + 255) / 256, 256, 0, stream>>>(srcs, dsts, cnt, esF);

    const long long MOFF1 = 50000ll * 128, MOFF2 = 70000ll * 128;
    const long long MOFF3 = 80000ll * 128, MOFF4 = 130000ll * 128;

    // ---- layer 1 (bf16 sources) ----
    P5 xs1 = {{xb_drug, xb_gene, xb_gene, xb_dis, xb_gene}};
    k_agg_all<<<(N_TOT + 3) / 4, 256, 0, stream>>>(xs1, cnt, esF, mean);
    k_gemm<true><<<(50000 + 63) / 64, 256, 0, stream>>>(
        mean, mean + MOFF3, mean + MOFF4, 3, xb_gene, Wg0, bg0, 1.0f / 3.0f,
        x1_gene, 50000);
    k_gemm<true><<<(20000 + 63) / 64, 256, 0, stream>>>(
        mean + MOFF1, nullptr, nullptr, 1, xb_drug, Wd0, bd0, 1.0f, x1_drug, 20000);
    k_gemm<true><<<(10000 + 63) / 64, 256, 0, stream>>>(
        mean + MOFF2, nullptr, nullptr, 1, xb_dis, Ws0, bs0, 1.0f, x1_dis, 10000);

    // ---- layer 2 ----
    P5 xs2 = {{x1_drug, x1_gene, x1_gene, x1_dis, x1_gene}};
    k_agg_all<<<(N_TOT + 3) / 4, 256, 0, stream>>>(xs2, cnt, esF, mean);

    float* outp = (float*)d_out;
    k_gemm<false><<<(20000 + 63) / 64, 256, 0, stream>>>(
        mean + MOFF1, nullptr, nullptr, 1, x1_drug, Wd1, bd1, 1.0f, outp, 20000);
    k_gemm<false><<<(10000 + 63) / 64, 256, 0, stream>>>(
        mean + MOFF2, nullptr, nullptr, 1, x1_dis, Ws1, bs1, 1.0f,
        outp + 20000ull * 128, 10000);
    k_gemm<false><<<(50000 + 63) / 64, 256, 0, stream>>>(
        mean, mean + MOFF3, mean + MOFF4, 3, x1_gene, Wg1, bg1, 1.0f / 3.0f,
        outp + 30000ull * 128, 50000);
}

// Round 9
// 598.580 us; speedup vs baseline: 2.5305x; 1.2017x over previous
//
#include <hip/hip_runtime.h>

typedef float floatx4 __attribute__((ext_vector_type(4)));
typedef short shortx8 __attribute__((ext_vector_type(8)));

struct P5 { const void* p[5]; };

__device__ __forceinline__ float bf16_to_f(unsigned short u) {
    union { unsigned int i; float f; } v;
    v.i = ((unsigned int)u) << 16;
    return v.f;
}
__device__ __forceinline__ unsigned short f_to_bf16(float f) {
    union { float f; unsigned int i; } v;
    v.f = f;
    unsigned int lsb = (v.i >> 16) & 1u;
    unsigned int r = v.i + 0x7fffu + lsb;
    return (unsigned short)(r >> 16);
}

#define E_TOT 2720000
#define N_TOT 180000
#define CAP 96        // max degree bound: worst-type mean 32, P(deg>=96) ~ 1e-20
#define NB_FILL 10625 // E_TOT / 256
#define NB_PREP 11024 // 10000 cast + 1024 build_w
#define NB_BUILD 21649

// ---------------- zero cnt ----------------
__global__ __launch_bounds__(256) void k_zero(int* __restrict__ p, int n) {
    int i = blockIdx.x * 256 + threadIdx.x;
    if (i < n) p[i] = 0;
}

// ---------------- build_w body (fp32 in, bf16 out) ----------------
// Wt layouts (bf16, [128 n x K k] row-major):
//  gene K=512: [Wl(e0)|Wl(e3)|Wl(e4)|Wr(e0)+Wr(e3)+Wr(e4)]
//  drug K=256: [Wl(e1)|Wr(e1)]   dis K=256: [Wl(e2)|Wr(e2)]
__device__ void build_w_body(const float* Wl, const float* Wr, const float* bl,
                             int l, int t,
                             unsigned short* Wg, unsigned short* Wd,
                             unsigned short* Ws, float* bg, float* bd, float* bs) {
    if (t < 128 * 512) {
        int n = t >> 9;
        int kg = t & 511;
        int b = kg >> 7, k = kg & 127;
        float v;
        if (b == 0)
            v = Wl[(((size_t)l * 5 + 0) * 128 + n) * 128 + k];
        else if (b == 1)
            v = Wl[(((size_t)l * 5 + 3) * 128 + n) * 128 + k];
        else if (b == 2)
            v = Wl[(((size_t)l * 5 + 4) * 128 + n) * 128 + k];
        else
            v = Wr[(((size_t)l * 5 + 0) * 128 + n) * 128 + k] +
                Wr[(((size_t)l * 5 + 3) * 128 + n) * 128 + k] +
                Wr[(((size_t)l * 5 + 4) * 128 + n) * 128 + k];
        Wg[n * 512 + kg] = f_to_bf16(v);
    } else if (t < 131072) {
        int t2 = t - 65536;
        int which = (t2 >= 32768) ? 1 : 0;  // 0=drug(e1), 1=disease(e2)
        int t3 = which ? t2 - 32768 : t2;
        int n = t3 >> 8;
        int kg = t3 & 255;
        int b = kg >> 7, k = kg & 127;
        int ei = which ? 2 : 1;
        float v = (b == 0) ? Wl[(((size_t)l * 5 + ei) * 128 + n) * 128 + k]
                           : Wr[(((size_t)l * 5 + ei) * 128 + n) * 128 + k];
        (which ? Ws : Wd)[n * 256 + kg] = f_to_bf16(v);
    }
    if (t < 128) {
        int n = t;
        bg[n] = bl[((size_t)l * 5 + 0) * 128 + n] +
                bl[((size_t)l * 5 + 3) * 128 + n] +
                bl[((size_t)l * 5 + 4) * 128 + n];
        bd[n] = bl[((size_t)l * 5 + 1) * 128 + n];
        bs[n] = bl[((size_t)l * 5 + 2) * 128 + n];
    }
}

// ---------------- merged build: fill (atomic, latency-bound) interleaved -----
// with cast+build_w (BW-bound) so both co-reside on every CU.
// even b<21250 -> fill b/2; odd -> prep b/2; b>=21250 -> prep 10625+(b-21250).
__global__ __launch_bounds__(256) void k_build(P5 src, P5 dst,
                                               int* __restrict__ cnt,
                                               unsigned short* __restrict__ esF,
                                               const float* __restrict__ drug,
                                               const float* __restrict__ dis,
                                               const float* __restrict__ gene,
                                               unsigned short* __restrict__ xb,
                                               const float* __restrict__ Wl,
                                               const float* __restrict__ Wr,
                                               const float* __restrict__ bl,
                                               unsigned short* __restrict__ Wg0,
                                               unsigned short* __restrict__ Wd0,
                                               unsigned short* __restrict__ Ws0,
                                               float* __restrict__ bg0,
                                               float* __restrict__ bd0,
                                               float* __restrict__ bs0,
                                               unsigned short* __restrict__ Wg1,
                                               unsigned short* __restrict__ Wd1,
                                               unsigned short* __restrict__ Ws1,
                                               float* __restrict__ bg1,
                                               float* __restrict__ bd1,
                                               float* __restrict__ bs1) {
    const int b = blockIdx.x;
    bool is_fill;
    int pb;  // partition-local block id
    if (b < 21250) {
        is_fill = (b & 1) == 0;
        pb = b >> 1;
    } else {
        is_fill = false;
        pb = 10625 + (b - 21250);
    }
    if (is_fill) {
        const int ebase[5] = {0, 640000, 1280000, 1600000, 1920000};
        const int noff[5]  = {0, 50000, 70000, 80000, 130000};
        int g = pb * 256 + threadIdx.x;
        if (g >= E_TOT) return;
        int t = (g < 640000) ? 0 : (g < 1280000) ? 1 : (g < 1600000) ? 2
                : (g < 1920000) ? 3 : 4;
        int e = g - ebase[t];
        int s = ((const int*)src.p[t])[e];
        int d = ((const int*)dst.p[t])[e];
        int w = noff[t] + d;
        int slot = atomicAdd(&cnt[w], 1);
        if (slot < CAP) esF[(size_t)w * CAP + slot] = (unsigned short)s;
    } else if (pb < 10000) {
        int i = (pb * 256 + threadIdx.x) * 4;
        if (i >= 10240000) return;
        const float* sp;
        int off;
        if (i < 2560000) { sp = drug; off = i; }
        else if (i < 3840000) { sp = dis; off = i - 2560000; }
        else { sp = gene; off = i - 3840000; }
        floatx4 v = *(const floatx4*)(sp + off);
        ushort4 r;
        r.x = f_to_bf16(v[0]);
        r.y = f_to_bf16(v[1]);
        r.z = f_to_bf16(v[2]);
        r.w = f_to_bf16(v[3]);
        *(ushort4*)(xb + i) = r;
    } else if (pb < 10512) {
        build_w_body(Wl, Wr, bl, 0, (pb - 10000) * 256 + threadIdx.x,
                     Wg0, Wd0, Ws0, bg0, bd0, bs0);
    } else {
        build_w_body(Wl, Wr, bl, 1, (pb - 10512) * 256 + threadIdx.x,
                     Wg1, Wd1, Ws1, bg1, bd1, bs1);
    }
}

// ---------------- fused aggregate over all 180000 (type,dst) slots -----------
// One wave per slot w; 4 lane-groups of 16 handle neighbors j..j+3; each lane
// covers 8 columns (16B loads); combine via shfl_xor(16,32); 16-lane store.
__global__ __launch_bounds__(256) void k_agg_all(P5 xs,
                                                 const int* __restrict__ cnt,
                                                 const unsigned short* __restrict__ esF,
                                                 unsigned short* __restrict__ mean) {
    int w = blockIdx.x * 4 + (threadIdx.x >> 6);
    if (w >= N_TOT) return;
    const int lane = threadIdx.x & 63;
    const int grp = lane >> 4;        // neighbor sub-index 0..3
    const int sub = lane & 15;        // 16 lanes cover one 256B row
    const int c0 = sub << 3;          // 8 cols per lane
    int t = (w < 50000) ? 0 : (w < 70000) ? 1 : (w < 80000) ? 2 : (w < 130000) ? 3 : 4;
    int n = cnt[w];
    if (n > CAP) n = CAP;
    if (n < 0) n = 0;
    const unsigned short* ep = esF + (size_t)w * CAP;
    const unsigned short* xp = (const unsigned short*)xs.p[t] + c0;
    float s0 = 0.f, s1 = 0.f, s2 = 0.f, s3 = 0.f;
    float s4 = 0.f, s5 = 0.f, s6 = 0.f, s7 = 0.f;
    int j = 0;
#pragma unroll 2
    for (; j + 4 <= n; j += 4) {
        int sA = ep[j + grp];
        uint4 p = *(const uint4*)(xp + ((size_t)sA << 7));
        s0 += bf16_to_f((unsigned short)(p.x & 0xffffu));
        s1 += bf16_to_f((unsigned short)(p.x >> 16));
        s2 += bf16_to_f((unsigned short)(p.y & 0xffffu));
        s3 += bf16_to_f((unsigned short)(p.y >> 16));
        s4 += bf16_to_f((unsigned short)(p.z & 0xffffu));
        s5 += bf16_to_f((unsigned short)(p.z >> 16));
        s6 += bf16_to_f((unsigned short)(p.w & 0xffffu));
        s7 += bf16_to_f((unsigned short)(p.w >> 16));
    }
    int rem = n - j;
    if (grp < rem) {
        int sA = ep[j + grp];
        uint4 p = *(const uint4*)(xp + ((size_t)sA << 7));
        s0 += bf16_to_f((unsigned short)(p.x & 0xffffu));
        s1 += bf16_to_f((unsigned short)(p.x >> 16));
        s2 += bf16_to_f((unsigned short)(p.y & 0xffffu));
        s3 += bf16_to_f((unsigned short)(p.y >> 16));
        s4 += bf16_to_f((unsigned short)(p.z & 0xffffu));
        s5 += bf16_to_f((unsigned short)(p.z >> 16));
        s6 += bf16_to_f((unsigned short)(p.w & 0xffffu));
        s7 += bf16_to_f((unsigned short)(p.w >> 16));
    }
    s0 += __shfl_xor(s0, 16); s1 += __shfl_xor(s1, 16);
    s2 += __shfl_xor(s2, 16); s3 += __shfl_xor(s3, 16);
    s4 += __shfl_xor(s4, 16); s5 += __shfl_xor(s5, 16);
    s6 += __shfl_xor(s6, 16); s7 += __shfl_xor(s7, 16);
    s0 += __shfl_xor(s0, 32); s1 += __shfl_xor(s1, 32);
    s2 += __shfl_xor(s2, 32); s3 += __shfl_xor(s3, 32);
    s4 += __shfl_xor(s4, 32); s5 += __shfl_xor(s5, 32);
    s6 += __shfl_xor(s6, 32); s7 += __shfl_xor(s7, 32);
    if (lane < 16) {
        float ic = 1.0f / (float)((n > 1) ? n : 1);
        uint4 o;
        o.x = (unsigned int)f_to_bf16(s0 * ic) | ((unsigned int)f_to_bf16(s1 * ic) << 16);
        o.y = (unsigned int)f_to_bf16(s2 * ic) | ((unsigned int)f_to_bf16(s3 * ic) << 16);
        o.z = (unsigned int)f_to_bf16(s4 * ic) | ((unsigned int)f_to_bf16(s5 * ic) << 16);
        o.w = (unsigned int)f_to_bf16(s6 * ic) | ((unsigned int)f_to_bf16(s7 * ic) << 16);
        *(uint4*)(mean + ((size_t)w << 7) + c0) = o;
    }
}

// ---------------- merged fused GEMM (3 jobs per layer) ----------------
// out[M,128] = relu( ( [m0|m1|m2|x] @ Wt^T + bias ) * invk )
// blocks [0,782) gene, [782,1095) drug, [1095,1252) dis.
struct GemmJob {
    const unsigned short *m0, *m1, *m2, *x, *Wt;
    const float* bias;
    float invk;
    void* out;
    int M, nacc;
};
struct Jobs { GemmJob j[3]; };

template <bool OUTBF>
__global__ __launch_bounds__(256) void k_gemm3(Jobs jobs) {
    const int b = blockIdx.x;
    int ji, bloc;
    if (b < 782) { ji = 0; bloc = b; }
    else if (b < 1095) { ji = 1; bloc = b - 782; }
    else { ji = 2; bloc = b - 1095; }
    const GemmJob& J = jobs.j[ji];
    const int K = (J.nacc + 1) << 7;
    const int lane = threadIdx.x & 63;
    const int wave = threadIdx.x >> 6;
    const int quad = lane >> 4;
    const int l16 = lane & 15;
    const int m_base = bloc * 64 + wave * 16;
    int row = m_base + l16;
    if (row > J.M - 1) row = J.M - 1;

    floatx4 acc[8];
#pragma unroll
    for (int i = 0; i < 8; i++) acc[i] = floatx4{0.f, 0.f, 0.f, 0.f};

    for (int s = 0; s <= J.nacc; s++) {
        const unsigned short* mp =
            ((s == J.nacc) ? J.x : (s == 0) ? J.m0 : (s == 1) ? J.m1 : J.m2) +
            ((size_t)row << 7);
#pragma unroll
        for (int kq = 0; kq < 4; kq++) {
            const int ko = (kq << 5) + (quad << 3);
            shortx8 afrag = *(const shortx8*)(mp + ko);
            const int kglob = (s << 7) + ko;
            const unsigned short* wp = J.Wt + (size_t)l16 * K + kglob;
#pragma unroll
            for (int nt = 0; nt < 8; nt++) {
                shortx8 bfrag = *(const shortx8*)(wp + ((size_t)(nt << 4)) * K);
                acc[nt] = __builtin_amdgcn_mfma_f32_16x16x32_bf16(afrag, bfrag, acc[nt], 0, 0, 0);
            }
        }
    }

    // epilogue: D mapping col=lane&15, row=quad*4+reg
#pragma unroll
    for (int nt = 0; nt < 8; nt++) {
        const int col = (nt << 4) + l16;
        const float bv = J.bias[col];
#pragma unroll
        for (int r = 0; r < 4; r++) {
            const int orow = m_base + (quad << 2) + r;
            if (orow < J.M) {
                float v = fmaxf((acc[nt][r] + bv) * J.invk, 0.f);
                if (OUTBF)
                    ((unsigned short*)J.out)[((size_t)orow << 7) + col] = f_to_bf16(v);
                else
                    ((float*)J.out)[((size_t)orow << 7) + col] = v;
            }
        }
    }
}

extern "C" void kernel_launch(void* const* d_in, const int* in_sizes, int n_in,
                              void* d_out, int out_size, void* d_ws, size_t ws_size,
                              hipStream_t stream) {
    const float* emb_drug = (const float*)d_in[0];
    const float* emb_dis  = (const float*)d_in[1];
    const float* emb_gene = (const float*)d_in[2];
    const float* Wl = (const float*)d_in[3];
    const float* Wr = (const float*)d_in[4];
    const float* bl = (const float*)d_in[5];
    P5 srcs = {{d_in[6], d_in[8], d_in[10], d_in[12], d_in[14]}};
    P5 dsts = {{d_in[7], d_in[9], d_in[11], d_in[13], d_in[15]}};

    char* base = (char*)d_ws;
    size_t off = 0;
    auto alloc = [&](size_t bytes) -> void* {
        void* r = base + off;
        off = (off + bytes + 255) & ~(size_t)255;
        return r;
    };
    int* cnt = (int*)alloc((size_t)N_TOT * 4);
    unsigned short* esF = (unsigned short*)alloc((size_t)N_TOT * CAP * 2);
    unsigned short* mean = (unsigned short*)alloc(180000ull * 128 * 2);
    unsigned short* xb = (unsigned short*)alloc(80000ull * 128 * 2);
    unsigned short* xb_drug = xb;
    unsigned short* xb_dis  = xb + 20000ull * 128;
    unsigned short* xb_gene = xb + 30000ull * 128;
    unsigned short* x1_drug = (unsigned short*)alloc(20000ull * 128 * 2);
    unsigned short* x1_dis  = (unsigned short*)alloc(10000ull * 128 * 2);
    unsigned short* x1_gene = (unsigned short*)alloc(50000ull * 128 * 2);
    unsigned short* Wg0 = (unsigned short*)alloc(128ull * 512 * 2);
    unsigned short* Wd0 = (unsigned short*)alloc(128ull * 256 * 2);
    unsigned short* Ws0 = (unsigned short*)alloc(128ull * 256 * 2);
    unsigned short* Wg1 = (unsigned short*)alloc(128ull * 512 * 2);
    unsigned short* Wd1 = (unsigned short*)alloc(128ull * 256 * 2);
    unsigned short* Ws1 = (unsigned short*)alloc(128ull * 256 * 2);
    float* bg0 = (float*)alloc(128 * 4);
    float* bd0 = (float*)alloc(128 * 4);
    float* bs0 = (float*)alloc(128 * 4);
    float* bg1 = (float*)alloc(128 * 4);
    float* bd1 = (float*)alloc(128 * 4);
    float* bs1 = (float*)alloc(128 * 4);

    // ---- zero counters, then merged fill+cast+build_w (interleaved blocks) ----
    k_zero<<<(N_TOT + 255) / 256, 256, 0, stream>>>(cnt, N_TOT);
    k_build<<<NB_BUILD, 256, 0, stream>>>(srcs, dsts, cnt, esF,
                                          emb_drug, emb_dis, emb_gene, xb,
                                          Wl, Wr, bl,
                                          Wg0, Wd0, Ws0, bg0, bd0, bs0,
                                          Wg1, Wd1, Ws1, bg1, bd1, bs1);

    const long long MOFF1 = 50000ll * 128, MOFF2 = 70000ll * 128;
    const long long MOFF3 = 80000ll * 128, MOFF4 = 130000ll * 128;

    // ---- layer 1 ----
    P5 xs1 = {{xb_drug, xb_gene, xb_gene, xb_dis, xb_gene}};
    k_agg_all<<<(N_TOT + 3) / 4, 256, 0, stream>>>(xs1, cnt, esF, mean);
    Jobs jobs1 = {{
        {mean, mean + MOFF3, mean + MOFF4, xb_gene, Wg0, bg0, 1.0f / 3.0f, x1_gene, 50000, 3},
        {mean + MOFF1, nullptr, nullptr, xb_drug, Wd0, bd0, 1.0f, x1_drug, 20000, 1},
        {mean + MOFF2, nullptr, nullptr, xb_dis, Ws0, bs0, 1.0f, x1_dis, 10000, 1},
    }};
    k_gemm3<true><<<1252, 256, 0, stream>>>(jobs1);

    // ---- layer 2 ----
    P5 xs2 = {{x1_drug, x1_gene, x1_gene, x1_dis, x1_gene}};
    k_agg_all<<<(N_TOT + 3) / 4, 256, 0, stream>>>(xs2, cnt, esF, mean);
    float* outp = (float*)d_out;
    Jobs jobs2 = {{
        {mean, mean + MOFF3, mean + MOFF4, x1_gene, Wg1, bg1, 1.0f / 3.0f,
         outp + 30000ull * 128, 50000, 3},
        {mean + MOFF1, nullptr, nullptr, x1_drug, Wd1, bd1, 1.0f, outp, 20000, 1},
        {mean + MOFF2, nullptr, nullptr, x1_dis, Ws1, bs1, 1.0f,
         outp + 20000ull * 128, 10000, 1},
    }};
    k_gemm3<false><<<1252, 256, 0, stream>>>(jobs2);
}